// Round 5
// baseline (1899.470 us; speedup 1.0000x reference)
//
#include <hip/hip_runtime.h>

// LSTM: B=512, T=1024, D=64, H=128, gates=4H=512, fc head H->64->1.
// 256 blocks (1/CU) x 512 threads, 2 batch rows/block.
// Evidence from rounds 1-4: per-step time is set by LDS-pipe issue count,
// not VALU. This version halves broadcast reads vs r3, eliminates the gate
// LDS array and r4's ds_bpermute shuffles (DPP quad-perm reductions are
// VALU), and runs ONE barrier per step.
// Thread (u = tid>>2, e = (tid>>1)&1, q = tid&1):
//   owns gate pair e ? {u+256 (g), u+384 (o)} : {u (i), u+128 (f)}
//   for K-half q of concat [h(128)|x(64)], BOTH batch rows.
//   96 f16x2 weight VGPRs; 192 asm v_dot2_f32_f16/step; 24 b128 LDS reads.
// Quad reduce: xor1 (q) completes K; xor2 (e) exchanges gate pairs; every
// lane then applies the full cell for both rows (c duplicated x4 lanes).

#define TT 1024
#define DD 64
#define HH 128
#define KK 192   // [h(128) | x(64)]

typedef _Float16 half2_t __attribute__((ext_vector_type(2)));

__device__ __forceinline__ float dot2(half2_t a, half2_t b, float c) {
    asm("v_dot2_f32_f16 %0, %1, %2, %0" : "+v"(c) : "v"(a), "v"(b));
    return c;
}

__device__ __forceinline__ half2_t bc(unsigned int u) {
    return __builtin_bit_cast(half2_t, u);
}

// quad_perm [1,0,3,2] = 0xB1 (swap bit0=q), [2,3,0,1] = 0x4E (swap bit1=e)
__device__ __forceinline__ float dpp_add_xor1(float x) {
    int y = __builtin_amdgcn_update_dpp(0, __builtin_bit_cast(int, x),
                                        0xB1, 0xF, 0xF, true);
    return x + __builtin_bit_cast(float, y);
}
__device__ __forceinline__ float dpp_mov_xor2(float x) {
    int y = __builtin_amdgcn_update_dpp(0, __builtin_bit_cast(int, x),
                                        0x4E, 0xF, 0xF, true);
    return __builtin_bit_cast(float, y);
}

__device__ __forceinline__ float sigm(float x) {
    return 1.f / (1.f + __expf(-x));
}
__device__ __forceinline__ float tanh_f(float x) {
    return 1.f - 2.f / (__expf(2.f * x) + 1.f);
}

// f16 pair of concat row [W_hh(128) | W_ih(64)] for gate row `gate`, even k
__device__ __forceinline__ half2_t wld(const float* __restrict__ Whh,
                                       const float* __restrict__ Wih,
                                       int gate, int k) {
    float2 f;
    if (k < HH) f = *reinterpret_cast<const float2*>(Whh + gate * HH + k);
    else        f = *reinterpret_cast<const float2*>(Wih + gate * DD + (k - HH));
    half2_t r;
    r[0] = (_Float16)f.x;
    r[1] = (_Float16)f.y;
    return r;
}

__global__ __launch_bounds__(512, 2)
void lstm_fused_kernel(const float* __restrict__ x_seq,
                       const float* __restrict__ W_ih,
                       const float* __restrict__ W_hh,
                       const float* __restrict__ b_ih,
                       const float* __restrict__ b_hh,
                       const float* __restrict__ W1v,
                       const float* __restrict__ b1v,
                       const float* __restrict__ W2v,
                       const float* __restrict__ b2v,
                       float* __restrict__ out)
{
    const int tid = threadIdx.x;
    const int q   = tid & 1;          // K-half
    const int e   = (tid >> 1) & 1;   // gate pair: 0 -> (i,f), 1 -> (g,o)
    const int u   = tid >> 2;         // hidden column 0..127
    const int b0  = blockIdx.x * 2;

    __shared__ __align__(16) _Float16 hx[2][2][KK];  // [buf][row][h|x]

    // ---- weights: 2 gates x 96 f16 (K-half) = 96 VGPRs ----
    const int g0 = u + e * 256;         // i or g
    const int g1 = u + 128 + e * 256;   // f or o
    const int kb = q * 96;
    half2_t w0[48], w1[48];
#pragma unroll
    for (int j = 0; j < 48; ++j) {
        w0[j] = wld(W_hh, W_ih, g0, kb + 2 * j);
        w1[j] = wld(W_hh, W_ih, g1, kb + 2 * j);
    }
    const float bI = b_ih[u]       + b_hh[u];
    const float bF = b_ih[u + 128] + b_hh[u + 128];
    const float bG = b_ih[u + 256] + b_hh[u + 256];
    const float bO = b_ih[u + 384] + b_hh[u + 384];

    // ---- init: h=0, x(0) into buffer 0 ----
    if (tid < 256) hx[0][tid >> 7][tid & 127] = (_Float16)0.f;
    if (tid < 128) {
        const int r = tid >> 6, k = tid & 63;
        hx[0][r][HH + k] = (_Float16)x_seq[((b0 + r) * TT + 0) * DD + k];
    }
    float c0 = 0.f, c1 = 0.f;  // both rows' c, duplicated across quad lanes

    // x-prefetch role: one lane per quad (q==1 && e==1), quad index u
    const bool is_pre = (q == 1) && (e == 1);
    const int  xr = u & 1, xk = u >> 1;
    __syncthreads();

    for (int t = 0; t < TT; ++t) {
        const int cur = t & 1, nxt = cur ^ 1;

        // issue next-x load early; latency hides under the dot2 block
        float xpre = 0.f;
        const bool pre = is_pre && (t + 1 < TT);
        if (pre) xpre = x_seq[((b0 + xr) * TT + (t + 1)) * DD + xk];

        const uint4* s0 = reinterpret_cast<const uint4*>(&hx[cur][0][0]) + q * 12;
        const uint4* s1 = reinterpret_cast<const uint4*>(&hx[cur][1][0]) + q * 12;

        // a<gate><row>: 4 accumulator chains, 192 dot2
        float a00 = 0.f, a01 = 0.f, a10 = 0.f, a11 = 0.f;
#pragma unroll
        for (int j = 0; j < 12; ++j) {
            const uint4 v0 = s0[j];
            const uint4 v1 = s1[j];
            a00 = dot2(w0[4 * j + 0], bc(v0.x), a00);
            a01 = dot2(w0[4 * j + 0], bc(v1.x), a01);
            a10 = dot2(w1[4 * j + 0], bc(v0.x), a10);
            a11 = dot2(w1[4 * j + 0], bc(v1.x), a11);
            a00 = dot2(w0[4 * j + 1], bc(v0.y), a00);
            a01 = dot2(w0[4 * j + 1], bc(v1.y), a01);
            a10 = dot2(w1[4 * j + 1], bc(v0.y), a10);
            a11 = dot2(w1[4 * j + 1], bc(v1.y), a11);
            a00 = dot2(w0[4 * j + 2], bc(v0.z), a00);
            a01 = dot2(w0[4 * j + 2], bc(v1.z), a01);
            a10 = dot2(w1[4 * j + 2], bc(v0.z), a10);
            a11 = dot2(w1[4 * j + 2], bc(v1.z), a11);
            a00 = dot2(w0[4 * j + 3], bc(v0.w), a00);
            a01 = dot2(w0[4 * j + 3], bc(v1.w), a01);
            a10 = dot2(w1[4 * j + 3], bc(v0.w), a10);
            a11 = dot2(w1[4 * j + 3], bc(v1.w), a11);
        }

        // ---- quad reduction, all on the VALU (DPP) ----
        a00 = dpp_add_xor1(a00);  // complete K across q
        a01 = dpp_add_xor1(a01);
        a10 = dpp_add_xor1(a10);
        a11 = dpp_add_xor1(a11);
        const float o00 = dpp_mov_xor2(a00);  // fetch other gate pair
        const float o01 = dpp_mov_xor2(a01);
        const float o10 = dpp_mov_xor2(a10);
        const float o11 = dpp_mov_xor2(a11);

        // e=0: own=(i,f), oth=(g,o); e=1: own=(g,o), oth=(i,f)
        const float gi0 = (e ? o00 : a00) + bI;
        const float gi1 = (e ? o01 : a01) + bI;
        const float gf0 = (e ? o10 : a10) + bF;
        const float gf1 = (e ? o11 : a11) + bF;
        const float gg0 = (e ? a00 : o00) + bG;
        const float gg1 = (e ? a01 : o01) + bG;
        const float go0 = (e ? a10 : o10) + bO;
        const float go1 = (e ? a11 : o11) + bO;

        // ---- cell, both rows, duplicated across the quad ----
        c0 = sigm(gf0) * c0 + sigm(gi0) * tanh_f(gg0);
        c1 = sigm(gf1) * c1 + sigm(gi1) * tanh_f(gg1);
        const float h0n = sigm(go0) * tanh_f(c0);
        const float h1n = sigm(go1) * tanh_f(c1);

        // one lane per (row,u) writes h'; prefetch lane writes x'
        if (e == 0) hx[nxt][q][u] = (_Float16)(q ? h1n : h0n);
        if (pre)    hx[nxt][xr][HH + xk] = (_Float16)xpre;
        __syncthreads();
    }

    // ---- fused head: z = relu(h @ W1^T + b1); y = z @ W2^T + b2 ----
    // final h is in hx[0] (TT even). wave 0 -> row 0, wave 1 -> row 1.
    if (tid < 128) {
        const int r = tid >> 6, j = tid & 63;
        float z = b1v[j];
        const float* w1 = W1v + j * HH;
#pragma unroll 16
        for (int k = 0; k < HH; ++k)
            z = fmaf(w1[k], (float)hx[0][r][k], z);
        z = fmaxf(z, 0.f) * W2v[j];
#pragma unroll
        for (int off = 32; off; off >>= 1)
            z += __shfl_down(z, off, 64);
        if (j == 0) out[b0 + r] = z + b2v[0];
    }
}

extern "C" void kernel_launch(void* const* d_in, const int* in_sizes, int n_in,
                              void* d_out, int out_size, void* d_ws, size_t ws_size,
                              hipStream_t stream) {
    const float* x_seq = (const float*)d_in[0];
    const float* W_ih  = (const float*)d_in[1];
    const float* W_hh  = (const float*)d_in[2];
    const float* b_ih  = (const float*)d_in[3];
    const float* b_hh  = (const float*)d_in[4];
    const float* W1    = (const float*)d_in[5];
    const float* b1    = (const float*)d_in[6];
    const float* W2    = (const float*)d_in[7];
    const float* b2    = (const float*)d_in[8];
    float* out = (float*)d_out;

    lstm_fused_kernel<<<256, 512, 0, stream>>>(
        x_seq, W_ih, W_hh, b_ih, b_hh, W1, b1, W2, b2, out);
}